// Round 4
// baseline (235.814 us; speedup 1.0000x reference)
//
#include <hip/hip_runtime.h>
#include <cmath>

typedef unsigned long long u64;
typedef __attribute__((ext_vector_type(2))) unsigned long long u64x2;

constexpr int      kLevels   = 12;
constexpr unsigned kHashSize = 1u << 19;            // 524288 entries/level
constexpr unsigned kHashMask = kHashSize - 1u;
constexpr int      kPoints   = 1 << 21;             // 2,097,152
constexpr int      kBlock    = 256;

// Levels 0..2 (line footprint ~2.2 MB total): gathered in the assemble pass.
// Levels 3..11: hash precomputed (pass 0), XCD-pinned phased gather (pass 1).
constexpr int kLowLevels = 3;
constexpr int kHiLevels  = kLevels - kLowLevels;    // 9

// ---- pass-0 geometry ----
constexpr int kHILP       = 4;
constexpr int kHashBlocks = kPoints / (kBlock * kHILP);   // 2048

// ---- pass-1 geometry ----
constexpr int kILP       = 8;
constexpr int kPtsPerBlk = kBlock * kILP;           // 2048
constexpr int kChunks    = kPoints / kPtsPerBlk;    // 1024 chunks/level
constexpr int kGBlocks   = kHiLevels * kChunks;     // 9216
constexpr int kXcds      = 8;
constexpr int kQLen      = kGBlocks / kXcds;        // 1152 (exact)

struct ResArr { float r[kLevels]; };

// ---------- Pass 0: read x ONCE, write hi-level hash indices -> d_out -----
// idx lives in d_out (75 MB of its 201 MB), which is dead until assemble
// overwrites it. Every store instr is 64x4 B contiguous (full lines, NT-safe).
__global__ __launch_bounds__(kBlock) void hash_kernel(
    const float* __restrict__ x,     // [N,3]
    unsigned*    __restrict__ idx,   // [9][N] u32
    ResArr res)
{
    const unsigned base = blockIdx.x * (unsigned)(kBlock * kHILP) + threadIdx.x;
#pragma unroll
    for (int k = 0; k < kHILP; ++k) {
        const unsigned p = base + (unsigned)(k * kBlock);
        const float px = x[p * 3u + 0u];
        const float py = x[p * 3u + 1u];
        const float pz = x[p * 3u + 2u];
#pragma unroll
        for (int li = 0; li < kHiLevels; ++li) {
            const float r = res.r[kLowLevels + li];
            const unsigned x0 = (unsigned)floorf(px * r);
            const unsigned y0 = (unsigned)floorf(py * r);
            const unsigned z0 = (unsigned)floorf(pz * r);
            const unsigned h  = (x0 ^ (y0 * 2654435761u) ^ (z0 * 805459861u)) & kHashMask;
            __builtin_nontemporal_store(h, idx + (size_t)li * kPoints + p);
        }
    }
}

// ---------- Pass 1: XCD-pinned level-phased gather (idx-driven) -> ws -----
// blockIdx % 8 picks the XCD; each XCD walks a level-major queue so its 4 MB
// L2 holds the one active table. No x reads, idx reads are coalesced 4 B.
__global__ __launch_bounds__(kBlock) void gather_hi_kernel(
    const unsigned* __restrict__ idx,   // [9][N]
    const u64*      __restrict__ emb,   // [L * 2^19] float2 as u64
    u64*            __restrict__ ws)    // [9][N]
{
    const unsigned b     = blockIdx.x;
    const unsigned g     = (b % (unsigned)kXcds) * (unsigned)kQLen
                         + (b / (unsigned)kXcds);
    const unsigned li    = g / (unsigned)kChunks;           // 0..8
    const unsigned chunk = g - li * (unsigned)kChunks;
    const unsigned level = li + (unsigned)kLowLevels;

    const u64*      __restrict__ tab  = emb + (size_t)level * kHashSize;
    const unsigned* __restrict__ idxl = idx + (size_t)li * kPoints;
    u64*            __restrict__ wsl  = ws  + (size_t)li * kPoints;
    const unsigned base = chunk * (unsigned)kPtsPerBlk + threadIdx.x;

#pragma unroll
    for (int k = 0; k < kILP; ++k) {
        const unsigned p = base + (unsigned)(k * kBlock);
        const unsigned h = __builtin_nontemporal_load(idxl + p);
        const u64 e = tab[h];                      // L2-resident gather
        __builtin_nontemporal_store(e, wsl + p);   // coalesced stream
    }
}

// ---------- Pass 2: gather levels 0..2 + read ws + LDS-staged assembly ----
// Every global store is 64 lanes x 16 B contiguous (full 64-B lines).
__global__ __launch_bounds__(kBlock) void assemble_kernel(
    const float* __restrict__ x,
    const u64*   __restrict__ emb,
    const u64*   __restrict__ ws,
    u64x2*       __restrict__ out,   // [N*6] of 16 B  (== [N,24] f32)
    ResArr res)
{
    __shared__ u64 lds[kBlock][kLevels + 1];       // +1 u64 pad
    const unsigned t    = threadIdx.x;
    const unsigned base = blockIdx.x * (unsigned)kBlock;
    const unsigned p    = base + t;

    const float px = x[p * 3u + 0u];
    const float py = x[p * 3u + 1u];
    const float pz = x[p * 3u + 2u];

#pragma unroll
    for (int l = 0; l < kLowLevels; ++l) {         // small tables: L2 hits
        const float r = res.r[l];
        const unsigned x0 = (unsigned)floorf(px * r);
        const unsigned y0 = (unsigned)floorf(py * r);
        const unsigned z0 = (unsigned)floorf(pz * r);
        const unsigned h  = (x0 ^ (y0 * 2654435761u) ^ (z0 * 805459861u)) & kHashMask;
        lds[t][l] = emb[(size_t)l * kHashSize + h];
    }
#pragma unroll
    for (int li = 0; li < kHiLevels; ++li) {       // coalesced 512 B/instr
        lds[t][kLowLevels + li] =
            __builtin_nontemporal_load(ws + (size_t)li * kPoints + p);
    }
    __syncthreads();

#pragma unroll
    for (int j = 0; j < 6; ++j) {
        const unsigned el = (unsigned)(j * kBlock) + t;   // 0..1535
        const unsigned p2 = el / 6u;
        const unsigned s2 = el - p2 * 6u;
        u64x2 o;
        o.x = lds[p2][2u * s2 + 0u];
        o.y = lds[p2][2u * s2 + 1u];
        __builtin_nontemporal_store(o, out + (size_t)base * 6u + el);
    }
}

// ---------- Fallback: round-1 direct kernel (if ws too small) -------------
__global__ __launch_bounds__(kBlock) void direct_kernel(
    const float* __restrict__ x,
    const u64*   __restrict__ emb,
    u64*         __restrict__ out,
    ResArr res)
{
    unsigned tid = blockIdx.x * (unsigned)kBlock + threadIdx.x;  // n*12 + l
    unsigned n   = tid / (unsigned)kLevels;
    unsigned l   = tid - n * (unsigned)kLevels;
    float r = res.r[0];
#pragma unroll
    for (int i = 1; i < kLevels; ++i) r = (l == (unsigned)i) ? res.r[i] : r;
    float px = x[n * 3u], py = x[n * 3u + 1u], pz = x[n * 3u + 2u];
    unsigned x0 = (unsigned)floorf(px * r);
    unsigned y0 = (unsigned)floorf(py * r);
    unsigned z0 = (unsigned)floorf(pz * r);
    unsigned h  = (x0 ^ (y0 * 2654435761u) ^ (z0 * 805459861u)) & kHashMask;
    __builtin_nontemporal_store(emb[l * kHashSize + h], out + tid);
}

extern "C" void kernel_launch(void* const* d_in, const int* in_sizes, int n_in,
                              void* d_out, int out_size, void* d_ws, size_t ws_size,
                              hipStream_t stream) {
    const float* x   = (const float*)d_in[0];
    const u64*   emb = (const u64*)d_in[1];

    // Replicate the reference's float64 resolution computation exactly.
    ResArr res;
    const double growth = std::exp((std::log(512.0) - std::log(16.0)) / 11.0);
    for (int i = 0; i < kLevels; ++i)
        res.r[i] = (float)(int)(16.0 * std::pow(growth, (double)i));

    const size_t ws_needed = (size_t)kHiLevels * kPoints * sizeof(u64); // 151 MB

    if (ws_size >= ws_needed) {
        unsigned* idx = (unsigned*)d_out;   // d_out doubles as idx scratch:
                                            // dead until assemble overwrites it
        hipLaunchKernelGGL(hash_kernel, dim3(kHashBlocks), dim3(kBlock), 0, stream,
                           x, idx, res);
        hipLaunchKernelGGL(gather_hi_kernel, dim3(kGBlocks), dim3(kBlock), 0, stream,
                           idx, emb, (u64*)d_ws);
        hipLaunchKernelGGL(assemble_kernel, dim3(kPoints / kBlock), dim3(kBlock), 0, stream,
                           x, emb, (const u64*)d_ws, (u64x2*)d_out, res);
    } else {
        const int total = kPoints * kLevels;
        hipLaunchKernelGGL(direct_kernel, dim3(total / kBlock), dim3(kBlock), 0, stream,
                           x, emb, (u64*)d_out, res);
    }
}

// Round 5
// 223.172 us; speedup vs baseline: 1.0566x; 1.0566x over previous
//
#include <hip/hip_runtime.h>
#include <cmath>

typedef unsigned long long u64;
typedef __attribute__((ext_vector_type(2))) unsigned long long u64x2;

constexpr int      kLevels   = 12;
constexpr unsigned kHashSize = 1u << 19;            // 524288 entries/level
constexpr unsigned kHashMask = kHashSize - 1u;
constexpr int      kPoints   = 1 << 21;             // 2,097,152
constexpr int      kBlock    = 256;

// Levels 0..2 (line footprint ~2.2 MB total): gathered in the assemble pass.
// Levels 3..11: hash precomputed (pass 0), XCD-pinned phased gather (pass 1).
constexpr int kLowLevels = 3;
constexpr int kHiLevels  = kLevels - kLowLevels;    // 9

// ---- pass-0 geometry ----
constexpr int kHILP       = 4;
constexpr int kHashBlocks = kPoints / (kBlock * kHILP);   // 2048

// ---- pass-1 geometry ----
constexpr int kILP       = 16;                      // gathers in flight per wave
constexpr int kPtsPerBlk = kBlock * kILP;           // 4096
constexpr int kChunks    = kPoints / kPtsPerBlk;    // 512 chunks/level
constexpr int kGBlocks   = kHiLevels * kChunks;     // 4608
constexpr int kXcds      = 8;
constexpr int kQLen      = kGBlocks / kXcds;        // 576 (exact)

struct ResArr { float r[kLevels]; };

// ---------- Pass 0: read x ONCE, write hi-level hash indices -> d_out -----
// idx lives in d_out (75 MB of its 201 MB), dead until assemble overwrites it.
__global__ __launch_bounds__(kBlock) void hash_kernel(
    const float* __restrict__ x,     // [N,3]
    unsigned*    __restrict__ idx,   // [9][N] u32
    ResArr res)
{
    const unsigned base = blockIdx.x * (unsigned)(kBlock * kHILP) + threadIdx.x;
#pragma unroll
    for (int k = 0; k < kHILP; ++k) {
        const unsigned p = base + (unsigned)(k * kBlock);
        const float px = x[p * 3u + 0u];
        const float py = x[p * 3u + 1u];
        const float pz = x[p * 3u + 2u];
#pragma unroll
        for (int li = 0; li < kHiLevels; ++li) {
            const float r = res.r[kLowLevels + li];
            const unsigned x0 = (unsigned)floorf(px * r);
            const unsigned y0 = (unsigned)floorf(py * r);
            const unsigned z0 = (unsigned)floorf(pz * r);
            const unsigned h  = (x0 ^ (y0 * 2654435761u) ^ (z0 * 805459861u)) & kHashMask;
            __builtin_nontemporal_store(h, idx + (size_t)li * kPoints + p);
        }
    }
}

// ---------- Pass 1: XCD-pinned, level-phased, MLP-batched gather ----------
// Three explicit phases (fenced with sched_barrier so the compiler cannot
// re-fuse them): load 16 indices -> issue 16 independent gathers back-to-back
// -> store 16 results. Keeps ~16 line-misses in flight PER WAVE instead of ~2.
__global__ __launch_bounds__(kBlock) void gather_hi_kernel(
    const unsigned* __restrict__ idx,   // [9][N]
    const u64*      __restrict__ emb,   // [L * 2^19] float2 as u64
    u64*            __restrict__ ws)    // [9][N]
{
    const unsigned b     = blockIdx.x;
    const unsigned g     = (b % (unsigned)kXcds) * (unsigned)kQLen
                         + (b / (unsigned)kXcds);
    const unsigned li    = g / (unsigned)kChunks;           // 0..8
    const unsigned chunk = g - li * (unsigned)kChunks;
    const unsigned level = li + (unsigned)kLowLevels;

    const u64*      __restrict__ tab  = emb + (size_t)level * kHashSize;
    const unsigned* __restrict__ idxl = idx + (size_t)li * kPoints;
    u64*            __restrict__ wsl  = ws  + (size_t)li * kPoints;
    const unsigned base = chunk * (unsigned)kPtsPerBlk + threadIdx.x;

    unsigned h[kILP];
#pragma unroll
    for (int k = 0; k < kILP; ++k)
        h[k] = __builtin_nontemporal_load(idxl + base + (unsigned)(k * kBlock));
    __builtin_amdgcn_sched_barrier(0);

    u64 e[kILP];
#pragma unroll
    for (int k = 0; k < kILP; ++k)      // 16 independent L2 gathers in flight
        e[k] = tab[h[k]];
    __builtin_amdgcn_sched_barrier(0);

#pragma unroll
    for (int k = 0; k < kILP; ++k)      // coalesced 512 B/instr stream
        __builtin_nontemporal_store(e[k], wsl + base + (unsigned)(k * kBlock));
}

// ---------- Pass 2: gather levels 0..2 + read ws + LDS-staged assembly ----
// Every global store is 64 lanes x 16 B contiguous (full 64-B lines).
__global__ __launch_bounds__(kBlock) void assemble_kernel(
    const float* __restrict__ x,
    const u64*   __restrict__ emb,
    const u64*   __restrict__ ws,
    u64x2*       __restrict__ out,   // [N*6] of 16 B  (== [N,24] f32)
    ResArr res)
{
    __shared__ u64 lds[kBlock][kLevels + 1];       // +1 u64 pad
    const unsigned t    = threadIdx.x;
    const unsigned base = blockIdx.x * (unsigned)kBlock;
    const unsigned p    = base + t;

    const float px = x[p * 3u + 0u];
    const float py = x[p * 3u + 1u];
    const float pz = x[p * 3u + 2u];

#pragma unroll
    for (int l = 0; l < kLowLevels; ++l) {         // small tables: L2 hits
        const float r = res.r[l];
        const unsigned x0 = (unsigned)floorf(px * r);
        const unsigned y0 = (unsigned)floorf(py * r);
        const unsigned z0 = (unsigned)floorf(pz * r);
        const unsigned h  = (x0 ^ (y0 * 2654435761u) ^ (z0 * 805459861u)) & kHashMask;
        lds[t][l] = emb[(size_t)l * kHashSize + h];
    }
#pragma unroll
    for (int li = 0; li < kHiLevels; ++li) {       // coalesced 512 B/instr
        lds[t][kLowLevels + li] =
            __builtin_nontemporal_load(ws + (size_t)li * kPoints + p);
    }
    __syncthreads();

#pragma unroll
    for (int j = 0; j < 6; ++j) {
        const unsigned el = (unsigned)(j * kBlock) + t;   // 0..1535
        const unsigned p2 = el / 6u;
        const unsigned s2 = el - p2 * 6u;
        u64x2 o;
        o.x = lds[p2][2u * s2 + 0u];
        o.y = lds[p2][2u * s2 + 1u];
        __builtin_nontemporal_store(o, out + (size_t)base * 6u + el);
    }
}

// ---------- Fallback: round-1 direct kernel (if ws too small) -------------
__global__ __launch_bounds__(kBlock) void direct_kernel(
    const float* __restrict__ x,
    const u64*   __restrict__ emb,
    u64*         __restrict__ out,
    ResArr res)
{
    unsigned tid = blockIdx.x * (unsigned)kBlock + threadIdx.x;  // n*12 + l
    unsigned n   = tid / (unsigned)kLevels;
    unsigned l   = tid - n * (unsigned)kLevels;
    float r = res.r[0];
#pragma unroll
    for (int i = 1; i < kLevels; ++i) r = (l == (unsigned)i) ? res.r[i] : r;
    float px = x[n * 3u], py = x[n * 3u + 1u], pz = x[n * 3u + 2u];
    unsigned x0 = (unsigned)floorf(px * r);
    unsigned y0 = (unsigned)floorf(py * r);
    unsigned z0 = (unsigned)floorf(pz * r);
    unsigned h  = (x0 ^ (y0 * 2654435761u) ^ (z0 * 805459861u)) & kHashMask;
    __builtin_nontemporal_store(emb[l * kHashSize + h], out + tid);
}

extern "C" void kernel_launch(void* const* d_in, const int* in_sizes, int n_in,
                              void* d_out, int out_size, void* d_ws, size_t ws_size,
                              hipStream_t stream) {
    const float* x   = (const float*)d_in[0];
    const u64*   emb = (const u64*)d_in[1];

    // Replicate the reference's float64 resolution computation exactly.
    ResArr res;
    const double growth = std::exp((std::log(512.0) - std::log(16.0)) / 11.0);
    for (int i = 0; i < kLevels; ++i)
        res.r[i] = (float)(int)(16.0 * std::pow(growth, (double)i));

    const size_t ws_needed = (size_t)kHiLevels * kPoints * sizeof(u64); // 151 MB

    if (ws_size >= ws_needed) {
        unsigned* idx = (unsigned*)d_out;   // d_out doubles as idx scratch
        hipLaunchKernelGGL(hash_kernel, dim3(kHashBlocks), dim3(kBlock), 0, stream,
                           x, idx, res);
        hipLaunchKernelGGL(gather_hi_kernel, dim3(kGBlocks), dim3(kBlock), 0, stream,
                           idx, emb, (u64*)d_ws);
        hipLaunchKernelGGL(assemble_kernel, dim3(kPoints / kBlock), dim3(kBlock), 0, stream,
                           x, emb, (const u64*)d_ws, (u64x2*)d_out, res);
    } else {
        const int total = kPoints * kLevels;
        hipLaunchKernelGGL(direct_kernel, dim3(total / kBlock), dim3(kBlock), 0, stream,
                           x, emb, (u64*)d_out, res);
    }
}